// Round 1
// baseline (439.704 us; speedup 1.0000x reference)
//
#include <hip/hip_runtime.h>
#include <hip/hip_bf16.h>

// Problem constants (B=4, S=2048, D=1024, H=16, DK=64)
#define BB 4
#define SS 2048
#define DD 1024
#define HH 16
#define DKK 64

typedef __bf16 bf16x8 __attribute__((ext_vector_type(8)));
typedef float floatx4 __attribute__((ext_vector_type(4)));

#if __has_builtin(__builtin_amdgcn_exp2f)
#define EXP2(x) __builtin_amdgcn_exp2f(x)
#else
#define EXP2(x) exp2f(x)
#endif

__device__ __forceinline__ float b2f(unsigned short u) {
    union { unsigned int i; float f; } c;
    c.i = ((unsigned int)u) << 16;
    return c.f;
}
__device__ __forceinline__ unsigned short f2b(float f) {
    unsigned int i = __float_as_uint(f);
    unsigned int r = (i + 0x7FFFu + ((i >> 16) & 1u)) >> 16;  // RNE
    return (unsigned short)r;
}
// cheap round-half-up bf16 pair pack: (lo, hi) -> u32
__device__ __forceinline__ unsigned int pkpair(float a, float b) {
    unsigned int ia = (__float_as_uint(a) + 0x8000u) >> 16;
    unsigned int ib = (__float_as_uint(b) + 0x8000u) & 0xffff0000u;
    return ia | ib;
}

// async global->LDS, 16 B per lane; LDS dst = wave-uniform base + lane*16
__device__ __forceinline__ void gload_lds16(const unsigned short* g,
                                            unsigned short* l) {
    __builtin_amdgcn_global_load_lds(
        (const __attribute__((address_space(1))) unsigned int*)g,
        (__attribute__((address_space(3))) unsigned int*)l, 16, 0, 0);
}

// ---------------------------------------------------------------------------
// fp32 -> bf16 conversion, 4 elems/thread
// ---------------------------------------------------------------------------
__global__ void cvt_f32_bf16(const float* __restrict__ in,
                             unsigned short* __restrict__ out, int n4) {
    int i = blockIdx.x * blockDim.x + threadIdx.x;
    if (i >= n4) return;
    float4 v = ((const float4*)in)[i];
    ushort4 o;
    o.x = f2b(v.x); o.y = f2b(v.y); o.z = f2b(v.z); o.w = f2b(v.w);
    ((ushort4*)out)[i] = o;
}

// ---------------------------------------------------------------------------
// m97-structure NT GEMM (unchanged).
// ---------------------------------------------------------------------------
template <typename CT>
__global__ void gemm_nt_lds(const unsigned short* __restrict__ A,
                            const unsigned short* __restrict__ B,
                            CT* __restrict__ C, int M, int N, int K) {
    __shared__ unsigned short Alds[128][32];
    __shared__ unsigned short Blds[128][32];

    const int tid  = threadIdx.x;
    const int lane = tid & 63;
    const int w    = tid >> 6;
    const int wm   = (w & 1) * 64;
    const int wn   = (w >> 1) * 64;

    const int m0 = blockIdx.x * 128;
    const int n0 = blockIdx.y * 128;

    const int row16 = lane & 15;
    const int part  = lane >> 4;
    const int rbase = part * 4;

    const int srow = lane >> 2;
    const int scol = (lane & 3) * 8;

    const unsigned short* Ag = A + (size_t)(m0 + w * 16 + srow) * K + scol;
    const unsigned short* Bg = B + (size_t)(n0 + w * 16 + srow) * K + scol;
    unsigned short* Al = &Alds[w * 16][0];
    unsigned short* Bl = &Blds[w * 16][0];
    const size_t rstep = (size_t)64 * K;

    floatx4 acc[4][4] = {};

    for (int k0 = 0; k0 < K; k0 += 32) {
        __syncthreads();
        gload_lds16(Ag + k0,         Al);
        gload_lds16(Ag + rstep + k0, Al + 64 * 32);
        gload_lds16(Bg + k0,         Bl);
        gload_lds16(Bg + rstep + k0, Bl + 64 * 32);
        __syncthreads();

        bf16x8 af[4], bfr[4];
#pragma unroll
        for (int i = 0; i < 4; ++i)
            af[i] = *(const bf16x8*)&Alds[wm + i * 16 + row16][part * 8];
#pragma unroll
        for (int j = 0; j < 4; ++j)
            bfr[j] = *(const bf16x8*)&Blds[wn + j * 16 + row16][part * 8];
#pragma unroll
        for (int i = 0; i < 4; ++i)
#pragma unroll
            for (int j = 0; j < 4; ++j)
                acc[i][j] = __builtin_amdgcn_mfma_f32_16x16x32_bf16(
                    af[i], bfr[j], acc[i][j], 0, 0, 0);
    }

#pragma unroll
    for (int i = 0; i < 4; ++i) {
#pragma unroll
        for (int j = 0; j < 4; ++j) {
            const int row = m0 + wm + i * 16 + rbase;
            const int col = n0 + wn + j * 16 + row16;
#pragma unroll
            for (int r = 0; r < 4; ++r) {
                size_t idx = (size_t)(row + r) * N + col;
                if constexpr (sizeof(CT) == 2) C[idx] = f2b(acc[i][j][r]);
                else                           C[idx] = acc[i][j][r];
            }
        }
    }
}

// ---------------------------------------------------------------------------
// repack_kv (unchanged): fragment-linear K / V^T tiles per (b,h,stile64).
// ---------------------------------------------------------------------------
__global__ void repack_kv(const unsigned short* __restrict__ qkv,
                          unsigned short* __restrict__ Kp,
                          unsigned short* __restrict__ Vt) {
    __shared__ unsigned short Vs[64][72];
    const int st = blockIdx.x, h = blockIdx.y, b = blockIdx.z;
    const int tid = threadIdx.x;
    const size_t base = ((size_t)((b * HH + h) * (SS / 64) + st)) * 4096;

#pragma unroll
    for (int p = 0; p < 2; ++p) {
        const int row = p * 32 + (tid >> 3);
        const int chunk = tid & 7;
        size_t src = (size_t)(b * SS + st * 64 + row) * (3 * DD) +
                     DD + h * DKK + chunk * 8;
        uint4 kv = *(const uint4*)(qkv + src);
        *(uint4*)(Kp + base + (chunk >> 2) * 2048 + row * 32 + (chunk & 3) * 8) = kv;
        uint4 vv = *(const uint4*)(qkv + src + DD);
        *(uint4*)&Vs[row][chunk * 8] = vv;
    }
    __syncthreads();
#pragma unroll
    for (int p = 0; p < 2; ++p) {
        const int dk = p * 32 + (tid >> 3);
        const int s8 = tid & 7;
        union { unsigned short u[8]; uint4 v; } pk;
#pragma unroll
        for (int j = 0; j < 8; ++j) pk.u[j] = Vs[s8 * 8 + j][dk];
        *(uint4*)(Vt + base + (s8 >> 2) * 2048 + dk * 32 + (s8 & 3) * 8) = pk.v;
    }
}

// ---------------------------------------------------------------------------
// MFMA flash attention v7 (causal): same LDS/barrier-free math as v6, but
// strip granularity halved 32 -> 16 q-rows to DOUBLE occupancy.
// Strip j in [0,128), q0 = 16*j, ntiles(j) = j/4 + 1. Complementary pairing
// j and 127-j gives ntA+ntB = 33 for EVERY wave (perfect balance).
// 4096 waves / 1024 blocks (4 blocks/CU, 4 waves/SIMD vs 2 before).
// Per-wave state halves (one 16-row q-tile per strip) so VGPR <= 128 holds.
// K/V fragments loaded once per tile feed both strips.
// ---------------------------------------------------------------------------
struct StripState {
    bf16x8 qf[2];
    floatx4 O[4];
    float mrow, lrow;
    int q0w;
};

__device__ __forceinline__ void strip_init(
    StripState& S, const unsigned short* __restrict__ qkv,
    int b, int h, int q0w, int row16, int part) {
    const float c1 = 0.180336884f;  // 0.125 * log2(e)
    S.q0w = q0w;
    S.mrow = -1e30f;
    S.lrow = 0.f;
#pragma unroll
    for (int dt = 0; dt < 4; ++dt) S.O[dt] = floatx4{0, 0, 0, 0};
#pragma unroll
    for (int u = 0; u < 2; ++u) {
        const unsigned short* qp = qkv +
            (size_t)(b * SS + q0w + row16) * (3 * DD) +
            h * DKK + u * 32 + part * 8;
        union { uint4 r; unsigned short us[8]; } raw;
        raw.r = *(const uint4*)qp;
        union { unsigned short us[8]; bf16x8 v; } sq;
#pragma unroll
        for (int j = 0; j < 8; ++j) sq.us[j] = f2b(b2f(raw.us[j]) * c1);
        S.qf[u] = sq.v;
    }
}

__device__ __forceinline__ void strip_tile(
    StripState& S, int k0, const bf16x8 kf[2][4], const bf16x8 vf[2][4],
    int row16, int part, int rbase) {
    // ---- S^T: lane holds q=row16, s = kt*16 + rbase + r ----
    floatx4 sc[4] = {};
#pragma unroll
    for (int u = 0; u < 2; ++u)
#pragma unroll
        for (int kt = 0; kt < 4; ++kt)
            sc[kt] = __builtin_amdgcn_mfma_f32_16x16x32_bf16(
                kf[u][kt], S.qf[u], sc[kt], 0, 0, 0);

    const int qa = S.q0w + row16;
    const bool full = (k0 + 63 <= S.q0w);
    float mx = -1e30f;
#pragma unroll
    for (int kt = 0; kt < 4; ++kt)
#pragma unroll
        for (int r = 0; r < 4; ++r) {
            float s = sc[kt][r];  // log2-scaled via Q
            if (!full) {
                int ka = k0 + kt * 16 + rbase + r;
                s = (ka <= qa) ? s : -1e30f;
            }
            sc[kt][r] = s;
            mx = fmaxf(mx, s);
        }
    mx = fmaxf(mx, __shfl_xor(mx, 16));
    mx = fmaxf(mx, __shfl_xor(mx, 32));
    float mnew = fmaxf(S.mrow, mx);
    float alpha = EXP2(S.mrow - mnew);

    float ps = 0.f;
    unsigned int pk[4][2];
#pragma unroll
    for (int kt = 0; kt < 4; ++kt) {
        float e0 = EXP2(sc[kt][0] - mnew);
        float e1 = EXP2(sc[kt][1] - mnew);
        float e2 = EXP2(sc[kt][2] - mnew);
        float e3 = EXP2(sc[kt][3] - mnew);
        ps += (e0 + e1) + (e2 + e3);
        pk[kt][0] = pkpair(e0, e1);
        pk[kt][1] = pkpair(e2, e3);
    }
    ps += __shfl_xor(ps, 16);
    ps += __shfl_xor(ps, 32);
    S.lrow = S.lrow * alpha + ps;
    S.mrow = mnew;

#pragma unroll
    for (int dt = 0; dt < 4; ++dt) S.O[dt] *= alpha;

    // ---- P^T B-frags (kt-select AFTER shuffle; dest-part algebra) ----
    const int l0 = row16 + ((part & 1) * 2 + 0) * 16;
    const int l1 = row16 + ((part & 1) * 2 + 1) * 16;
    const bool hi = (part >> 1);
#pragma unroll
    for (int u = 0; u < 2; ++u) {
        unsigned int lo00 = (unsigned int)__shfl((int)pk[2 * u][0], l0);
        unsigned int lo01 = (unsigned int)__shfl((int)pk[2 * u][1], l0);
        unsigned int lo10 = (unsigned int)__shfl((int)pk[2 * u][0], l1);
        unsigned int lo11 = (unsigned int)__shfl((int)pk[2 * u][1], l1);
        unsigned int hi00 = (unsigned int)__shfl((int)pk[2 * u + 1][0], l0);
        unsigned int hi01 = (unsigned int)__shfl((int)pk[2 * u + 1][1], l0);
        unsigned int hi10 = (unsigned int)__shfl((int)pk[2 * u + 1][0], l1);
        unsigned int hi11 = (unsigned int)__shfl((int)pk[2 * u + 1][1], l1);
        union { unsigned int u32[4]; bf16x8 v; } P;
        P.u32[0] = hi ? hi00 : lo00;
        P.u32[1] = hi ? hi01 : lo01;
        P.u32[2] = hi ? hi10 : lo10;
        P.u32[3] = hi ? hi11 : lo11;
#pragma unroll
        for (int dt = 0; dt < 4; ++dt)
            S.O[dt] = __builtin_amdgcn_mfma_f32_16x16x32_bf16(
                vf[u][dt], P.v, S.O[dt], 0, 0, 0);
    }
}

__device__ __forceinline__ void strip_store(
    StripState& S, unsigned short* __restrict__ heads,
    int b, int h, int row16, int rbase) {
    float inv = 1.f / S.lrow;
#pragma unroll
    for (int dt = 0; dt < 4; ++dt) {
        ushort4 o4;
        o4.x = f2b(S.O[dt][0] * inv);
        o4.y = f2b(S.O[dt][1] * inv);
        o4.z = f2b(S.O[dt][2] * inv);
        o4.w = f2b(S.O[dt][3] * inv);
        size_t base = (size_t)(b * SS + S.q0w + row16) * DD +
                      h * DKK + dt * 16 + rbase;
        *(ushort4*)&heads[base] = o4;
    }
}

__global__ __launch_bounds__(256, 4) void attn_mfma7(
    const unsigned short* __restrict__ qkv,
    const unsigned short* __restrict__ Kp,
    const unsigned short* __restrict__ Vt,
    unsigned short* __restrict__ heads) {
    const int tid  = threadIdx.x;
    const int lane = tid & 63;
    const int w    = tid >> 6;

    // XCD mapping: 16 blocks of one (b,h) pinned to xcd = bx & 7
    const int bx   = blockIdx.x;              // 0..1023
    const int xcd  = bx & 7;
    const int slot = bx >> 3;                 // 0..127
    const int pair = xcd * 8 + (slot >> 4);   // 0..63 = b*16+h
    const int blk  = slot & 15;               // 0..15
    const int b = pair >> 4, h = pair & 15;

    const int jA = blk * 4 + w;               // 0..63  (light strip, 16 rows)
    const int jB = 127 - jA;                  // 64..127 (heavy strip)
    const int ntA = jA / 4 + 1;               // tiles for strip A
    const int ntB = jB / 4 + 1;               // tiles for strip B (>= 17)

    const int row16 = lane & 15;
    const int part  = lane >> 4;
    const int rbase = part * 4;

    StripState SA, SB;
    strip_init(SA, qkv, b, h, jA * 16, row16, part);
    strip_init(SB, qkv, b, h, jB * 16, row16, part);

    const size_t tb = (size_t)pair * (SS / 64) * 4096;

    for (int t = 0; t < ntB; ++t) {
        const int k0 = t * 64;
        const unsigned short* kbase = Kp + tb + (size_t)t * 4096;
        const unsigned short* vbase = Vt + tb + (size_t)t * 4096;
        bf16x8 kf[2][4], vf[2][4];
#pragma unroll
        for (int u = 0; u < 2; ++u)
#pragma unroll
            for (int i = 0; i < 4; ++i) {
                kf[u][i] = *(const bf16x8*)(kbase + u * 2048 +
                                            (i * 16 + row16) * 32 + part * 8);
                vf[u][i] = *(const bf16x8*)(vbase + u * 2048 +
                                            (i * 16 + row16) * 32 + part * 8);
            }
        strip_tile(SB, k0, kf, vf, row16, part, rbase);
        if (t < ntA) strip_tile(SA, k0, kf, vf, row16, part, rbase);
    }

    strip_store(SA, heads, b, h, row16, rbase);
    strip_store(SB, heads, b, h, row16, rbase);
}

// ---------------------------------------------------------------------------
extern "C" void kernel_launch(void* const* d_in, const int* in_sizes, int n_in,
                              void* d_out, int out_size, void* d_ws,
                              size_t ws_size, hipStream_t stream) {
    const float* x    = (const float*)d_in[0];
    const float* Wqkv = (const float*)d_in[1];
    const float* Wo   = (const float*)d_in[2];
    float* out = (float*)d_out;

    const size_t NX  = (size_t)BB * SS * DD;
    const size_t NWQ = (size_t)3 * DD * DD;
    const size_t NWO = (size_t)DD * DD;
    const size_t NKV = (size_t)BB * HH * SS * DKK;

    unsigned short* xb     = (unsigned short*)d_ws;
    unsigned short* wqkvb  = xb + NX;
    unsigned short* wob    = wqkvb + NWQ;
    unsigned short* qkvb   = wob + NWO;
    unsigned short* headsb = qkvb + (size_t)BB * SS * 3 * DD;
    unsigned short* Kp     = headsb + NX;
    unsigned short* Vtp    = Kp + NKV;

    cvt_f32_bf16<<<(int)(NX / 4 / 256), 256, 0, stream>>>(x, xb, (int)(NX / 4));
    cvt_f32_bf16<<<(int)(NWQ / 4 / 256), 256, 0, stream>>>(Wqkv, wqkvb, (int)(NWQ / 4));
    cvt_f32_bf16<<<(int)(NWO / 4 / 256), 256, 0, stream>>>(Wo, wob, (int)(NWO / 4));

    // QKV projection
    gemm_nt_lds<unsigned short><<<dim3(BB * SS / 128, 3 * DD / 128), 256, 0,
                                  stream>>>(xb, wqkvb, qkvb, BB * SS, 3 * DD, DD);

    // repack K/V into MFMA-ready fragment-linear tiles
    repack_kv<<<dim3(SS / 64, HH, BB), 256, 0, stream>>>(qkvb, Kp, Vtp);

    // causal MFMA attention (balanced complementary 16-row strips, 4 blk/CU)
    attn_mfma7<<<dim3(1024), 256, 0, stream>>>(qkvb, Kp, Vtp, headsb);

    // output projection
    gemm_nt_lds<float><<<dim3(BB * SS / 128, DD / 128), 256, 0, stream>>>(
        headsb, wob, out, BB * SS, DD, DD);
}

// Round 2
// 319.645 us; speedup vs baseline: 1.3756x; 1.3756x over previous
//
#include <hip/hip_runtime.h>
#include <hip/hip_bf16.h>

// Problem constants (B=4, S=2048, D=1024, H=16, DK=64)
#define BB 4
#define SS 2048
#define DD 1024
#define HH 16
#define DKK 64

typedef __bf16 bf16x8 __attribute__((ext_vector_type(8)));
typedef float floatx4 __attribute__((ext_vector_type(4)));

#if __has_builtin(__builtin_amdgcn_exp2f)
#define EXP2(x) __builtin_amdgcn_exp2f(x)
#else
#define EXP2(x) exp2f(x)
#endif

__device__ __forceinline__ float b2f(unsigned short u) {
    union { unsigned int i; float f; } c;
    c.i = ((unsigned int)u) << 16;
    return c.f;
}
__device__ __forceinline__ unsigned short f2b(float f) {
    unsigned int i = __float_as_uint(f);
    unsigned int r = (i + 0x7FFFu + ((i >> 16) & 1u)) >> 16;  // RNE
    return (unsigned short)r;
}
// cheap round-half-up bf16 pair pack: (lo, hi) -> u32
__device__ __forceinline__ unsigned int pkpair(float a, float b) {
    unsigned int ia = (__float_as_uint(a) + 0x8000u) >> 16;
    unsigned int ib = (__float_as_uint(b) + 0x8000u) & 0xffff0000u;
    return ia | ib;
}

// async global->LDS, 16 B per lane; LDS dst = wave-uniform base + lane*16
__device__ __forceinline__ void gload_lds16(const unsigned short* g,
                                            unsigned short* l) {
    __builtin_amdgcn_global_load_lds(
        (const __attribute__((address_space(1))) unsigned int*)g,
        (__attribute__((address_space(3))) unsigned int*)l, 16, 0, 0);
}

// ---------------------------------------------------------------------------
// fp32 -> bf16 conversion, 4 elems/thread
// ---------------------------------------------------------------------------
__global__ void cvt_f32_bf16(const float* __restrict__ in,
                             unsigned short* __restrict__ out, int n4) {
    int i = blockIdx.x * blockDim.x + threadIdx.x;
    if (i >= n4) return;
    float4 v = ((const float4*)in)[i];
    ushort4 o;
    o.x = f2b(v.x); o.y = f2b(v.y); o.z = f2b(v.z); o.w = f2b(v.w);
    ((ushort4*)out)[i] = o;
}

// ---------------------------------------------------------------------------
// m97-structure NT GEMM (unchanged).
// ---------------------------------------------------------------------------
template <typename CT>
__global__ void gemm_nt_lds(const unsigned short* __restrict__ A,
                            const unsigned short* __restrict__ B,
                            CT* __restrict__ C, int M, int N, int K) {
    __shared__ unsigned short Alds[128][32];
    __shared__ unsigned short Blds[128][32];

    const int tid  = threadIdx.x;
    const int lane = tid & 63;
    const int w    = tid >> 6;
    const int wm   = (w & 1) * 64;
    const int wn   = (w >> 1) * 64;

    const int m0 = blockIdx.x * 128;
    const int n0 = blockIdx.y * 128;

    const int row16 = lane & 15;
    const int part  = lane >> 4;
    const int rbase = part * 4;

    const int srow = lane >> 2;
    const int scol = (lane & 3) * 8;

    const unsigned short* Ag = A + (size_t)(m0 + w * 16 + srow) * K + scol;
    const unsigned short* Bg = B + (size_t)(n0 + w * 16 + srow) * K + scol;
    unsigned short* Al = &Alds[w * 16][0];
    unsigned short* Bl = &Blds[w * 16][0];
    const size_t rstep = (size_t)64 * K;

    floatx4 acc[4][4] = {};

    for (int k0 = 0; k0 < K; k0 += 32) {
        __syncthreads();
        gload_lds16(Ag + k0,         Al);
        gload_lds16(Ag + rstep + k0, Al + 64 * 32);
        gload_lds16(Bg + k0,         Bl);
        gload_lds16(Bg + rstep + k0, Bl + 64 * 32);
        __syncthreads();

        bf16x8 af[4], bfr[4];
#pragma unroll
        for (int i = 0; i < 4; ++i)
            af[i] = *(const bf16x8*)&Alds[wm + i * 16 + row16][part * 8];
#pragma unroll
        for (int j = 0; j < 4; ++j)
            bfr[j] = *(const bf16x8*)&Blds[wn + j * 16 + row16][part * 8];
#pragma unroll
        for (int i = 0; i < 4; ++i)
#pragma unroll
            for (int j = 0; j < 4; ++j)
                acc[i][j] = __builtin_amdgcn_mfma_f32_16x16x32_bf16(
                    af[i], bfr[j], acc[i][j], 0, 0, 0);
    }

#pragma unroll
    for (int i = 0; i < 4; ++i) {
#pragma unroll
        for (int j = 0; j < 4; ++j) {
            const int row = m0 + wm + i * 16 + rbase;
            const int col = n0 + wn + j * 16 + row16;
#pragma unroll
            for (int r = 0; r < 4; ++r) {
                size_t idx = (size_t)(row + r) * N + col;
                if constexpr (sizeof(CT) == 2) C[idx] = f2b(acc[i][j][r]);
                else                           C[idx] = acc[i][j][r];
            }
        }
    }
}

// ---------------------------------------------------------------------------
// repack_kv (unchanged): fragment-linear K / V^T tiles per (b,h,stile64).
// ---------------------------------------------------------------------------
__global__ void repack_kv(const unsigned short* __restrict__ qkv,
                          unsigned short* __restrict__ Kp,
                          unsigned short* __restrict__ Vt) {
    __shared__ unsigned short Vs[64][72];
    const int st = blockIdx.x, h = blockIdx.y, b = blockIdx.z;
    const int tid = threadIdx.x;
    const size_t base = ((size_t)((b * HH + h) * (SS / 64) + st)) * 4096;

#pragma unroll
    for (int p = 0; p < 2; ++p) {
        const int row = p * 32 + (tid >> 3);
        const int chunk = tid & 7;
        size_t src = (size_t)(b * SS + st * 64 + row) * (3 * DD) +
                     DD + h * DKK + chunk * 8;
        uint4 kv = *(const uint4*)(qkv + src);
        *(uint4*)(Kp + base + (chunk >> 2) * 2048 + row * 32 + (chunk & 3) * 8) = kv;
        uint4 vv = *(const uint4*)(qkv + src + DD);
        *(uint4*)&Vs[row][chunk * 8] = vv;
    }
    __syncthreads();
#pragma unroll
    for (int p = 0; p < 2; ++p) {
        const int dk = p * 32 + (tid >> 3);
        const int s8 = tid & 7;
        union { unsigned short u[8]; uint4 v; } pk;
#pragma unroll
        for (int j = 0; j < 8; ++j) pk.u[j] = Vs[s8 * 8 + j][dk];
        *(uint4*)(Vt + base + (s8 >> 2) * 2048 + dk * 32 + (s8 & 3) * 8) = pk.v;
    }
}

// ---------------------------------------------------------------------------
// MFMA flash attention v8 (causal): ONE 16-row strip per wave (TLP replaces
// the register-funded strip-pairing ILP of v6/v7). 8192 waves / 2048 blocks
// = 4 blocks/CU at <=128 unified VGPRs (the v7 spill is avoided by streaming
// K-frags then V-frags through the SAME register slot: K dies after S^T,
// V loads after softmax). Load balance: strip j costs j/4+1 tiles; heavy
// strips are mapped to LOW blockIdx (LPT order - dispatch drains long jobs
// first, short ones backfill). XCD mapping: 8 (b,h) pairs pinned per XCD
// (8 x 512KB K/V = 4MB = one L2).
// ---------------------------------------------------------------------------
struct StripState {
    bf16x8 qf[2];
    floatx4 O[4];
    float mrow, lrow;
    int q0w;
};

__device__ __forceinline__ void strip_init(
    StripState& S, const unsigned short* __restrict__ qkv,
    int b, int h, int q0w, int row16, int part) {
    const float c1 = 0.180336884f;  // 0.125 * log2(e)
    S.q0w = q0w;
    S.mrow = -1e30f;
    S.lrow = 0.f;
#pragma unroll
    for (int dt = 0; dt < 4; ++dt) S.O[dt] = floatx4{0, 0, 0, 0};
#pragma unroll
    for (int u = 0; u < 2; ++u) {
        const unsigned short* qp = qkv +
            (size_t)(b * SS + q0w + row16) * (3 * DD) +
            h * DKK + u * 32 + part * 8;
        union { uint4 r; unsigned short us[8]; } raw;
        raw.r = *(const uint4*)qp;
        union { unsigned short us[8]; bf16x8 v; } sq;
#pragma unroll
        for (int j = 0; j < 8; ++j) sq.us[j] = f2b(b2f(raw.us[j]) * c1);
        S.qf[u] = sq.v;
    }
}

__device__ __forceinline__ void strip_tile(
    StripState& S, int k0,
    const unsigned short* __restrict__ kbase,
    const unsigned short* __restrict__ vbase,
    int row16, int part, int rbase) {
    // ---- S^T = K·Q^T: K-frags streamed, die after use ----
    floatx4 sc[4] = {};
#pragma unroll
    for (int u = 0; u < 2; ++u) {
        bf16x8 kf[4];
#pragma unroll
        for (int kt = 0; kt < 4; ++kt)
            kf[kt] = *(const bf16x8*)(kbase + u * 2048 +
                                      (kt * 16 + row16) * 32 + part * 8);
#pragma unroll
        for (int kt = 0; kt < 4; ++kt)
            sc[kt] = __builtin_amdgcn_mfma_f32_16x16x32_bf16(
                kf[kt], S.qf[u], sc[kt], 0, 0, 0);
    }

    const int qa = S.q0w + row16;
    const bool full = (k0 + 63 <= S.q0w);
    float mx = -1e30f;
#pragma unroll
    for (int kt = 0; kt < 4; ++kt)
#pragma unroll
        for (int r = 0; r < 4; ++r) {
            float s = sc[kt][r];  // log2-scaled via Q
            if (!full) {
                int ka = k0 + kt * 16 + rbase + r;
                s = (ka <= qa) ? s : -1e30f;
            }
            sc[kt][r] = s;
            mx = fmaxf(mx, s);
        }
    mx = fmaxf(mx, __shfl_xor(mx, 16));
    mx = fmaxf(mx, __shfl_xor(mx, 32));
    float mnew = fmaxf(S.mrow, mx);
    float alpha = EXP2(S.mrow - mnew);

    float ps = 0.f;
    unsigned int pk[4][2];
#pragma unroll
    for (int kt = 0; kt < 4; ++kt) {
        float e0 = EXP2(sc[kt][0] - mnew);
        float e1 = EXP2(sc[kt][1] - mnew);
        float e2 = EXP2(sc[kt][2] - mnew);
        float e3 = EXP2(sc[kt][3] - mnew);
        ps += (e0 + e1) + (e2 + e3);
        pk[kt][0] = pkpair(e0, e1);
        pk[kt][1] = pkpair(e2, e3);
    }
    ps += __shfl_xor(ps, 16);
    ps += __shfl_xor(ps, 32);
    S.lrow = S.lrow * alpha + ps;
    S.mrow = mnew;

#pragma unroll
    for (int dt = 0; dt < 4; ++dt) S.O[dt] *= alpha;

    // ---- PV: V-frags reuse K's register slot (loaded after softmax) ----
    const int l0 = row16 + ((part & 1) * 2 + 0) * 16;
    const int l1 = row16 + ((part & 1) * 2 + 1) * 16;
    const bool hi = (part >> 1);
#pragma unroll
    for (int u = 0; u < 2; ++u) {
        bf16x8 vf[4];
#pragma unroll
        for (int dt = 0; dt < 4; ++dt)
            vf[dt] = *(const bf16x8*)(vbase + u * 2048 +
                                      (dt * 16 + row16) * 32 + part * 8);
        unsigned int lo00 = (unsigned int)__shfl((int)pk[2 * u][0], l0);
        unsigned int lo01 = (unsigned int)__shfl((int)pk[2 * u][1], l0);
        unsigned int lo10 = (unsigned int)__shfl((int)pk[2 * u][0], l1);
        unsigned int lo11 = (unsigned int)__shfl((int)pk[2 * u][1], l1);
        unsigned int hi00 = (unsigned int)__shfl((int)pk[2 * u + 1][0], l0);
        unsigned int hi01 = (unsigned int)__shfl((int)pk[2 * u + 1][1], l0);
        unsigned int hi10 = (unsigned int)__shfl((int)pk[2 * u + 1][0], l1);
        unsigned int hi11 = (unsigned int)__shfl((int)pk[2 * u + 1][1], l1);
        union { unsigned int u32[4]; bf16x8 v; } P;
        P.u32[0] = hi ? hi00 : lo00;
        P.u32[1] = hi ? hi01 : lo01;
        P.u32[2] = hi ? hi10 : lo10;
        P.u32[3] = hi ? hi11 : lo11;
#pragma unroll
        for (int dt = 0; dt < 4; ++dt)
            S.O[dt] = __builtin_amdgcn_mfma_f32_16x16x32_bf16(
                vf[dt], P.v, S.O[dt], 0, 0, 0);
    }
}

__device__ __forceinline__ void strip_store(
    StripState& S, unsigned short* __restrict__ heads,
    int b, int h, int row16, int rbase) {
    float inv = 1.f / S.lrow;
#pragma unroll
    for (int dt = 0; dt < 4; ++dt) {
        ushort4 o4;
        o4.x = f2b(S.O[dt][0] * inv);
        o4.y = f2b(S.O[dt][1] * inv);
        o4.z = f2b(S.O[dt][2] * inv);
        o4.w = f2b(S.O[dt][3] * inv);
        size_t base = (size_t)(b * SS + S.q0w + row16) * DD +
                      h * DKK + dt * 16 + rbase;
        *(ushort4*)&heads[base] = o4;
    }
}

__global__ __launch_bounds__(256, 4) void attn_mfma8(
    const unsigned short* __restrict__ qkv,
    const unsigned short* __restrict__ Kp,
    const unsigned short* __restrict__ Vt,
    unsigned short* __restrict__ heads) {
    const int tid  = threadIdx.x;
    const int lane = tid & 63;
    const int w    = tid >> 6;

    // bx: 0..2047. XCD pinning + LPT (heavy strips at low blockIdx).
    const int bx   = blockIdx.x;
    const int xcd  = bx & 7;
    const int idx  = bx >> 3;                 // 0..255
    const int quad = idx >> 3;                // 0..31  (strip quad, LPT order)
    const int pr   = idx & 7;                 // 0..7   ((b,h) within XCD)
    const int pair = xcd * 8 + pr;            // 0..63 = b*16+h
    const int b = pair >> 4, h = pair & 15;

    const int j  = 127 - (quad * 4 + w);      // strip index, heavy first
    const int nt = j / 4 + 1;                 // causal tile count

    const int row16 = lane & 15;
    const int part  = lane >> 4;
    const int rbase = part * 4;

    StripState S;
    strip_init(S, qkv, b, h, j * 16, row16, part);

    const size_t tb = (size_t)pair * (SS / 64) * 4096;

    for (int t = 0; t < nt; ++t) {
        strip_tile(S, t * 64, Kp + tb + (size_t)t * 4096,
                   Vt + tb + (size_t)t * 4096, row16, part, rbase);
    }

    strip_store(S, heads, b, h, row16, rbase);
}

// ---------------------------------------------------------------------------
extern "C" void kernel_launch(void* const* d_in, const int* in_sizes, int n_in,
                              void* d_out, int out_size, void* d_ws,
                              size_t ws_size, hipStream_t stream) {
    const float* x    = (const float*)d_in[0];
    const float* Wqkv = (const float*)d_in[1];
    const float* Wo   = (const float*)d_in[2];
    float* out = (float*)d_out;

    const size_t NX  = (size_t)BB * SS * DD;
    const size_t NWQ = (size_t)3 * DD * DD;
    const size_t NWO = (size_t)DD * DD;
    const size_t NKV = (size_t)BB * HH * SS * DKK;

    unsigned short* xb     = (unsigned short*)d_ws;
    unsigned short* wqkvb  = xb + NX;
    unsigned short* wob    = wqkvb + NWQ;
    unsigned short* qkvb   = wob + NWO;
    unsigned short* headsb = qkvb + (size_t)BB * SS * 3 * DD;
    unsigned short* Kp     = headsb + NX;
    unsigned short* Vtp    = Kp + NKV;

    cvt_f32_bf16<<<(int)(NX / 4 / 256), 256, 0, stream>>>(x, xb, (int)(NX / 4));
    cvt_f32_bf16<<<(int)(NWQ / 4 / 256), 256, 0, stream>>>(Wqkv, wqkvb, (int)(NWQ / 4));
    cvt_f32_bf16<<<(int)(NWO / 4 / 256), 256, 0, stream>>>(Wo, wob, (int)(NWO / 4));

    // QKV projection
    gemm_nt_lds<unsigned short><<<dim3(BB * SS / 128, 3 * DD / 128), 256, 0,
                                  stream>>>(xb, wqkvb, qkvb, BB * SS, 3 * DD, DD);

    // repack K/V into MFMA-ready fragment-linear tiles
    repack_kv<<<dim3(SS / 64, HH, BB), 256, 0, stream>>>(qkvb, Kp, Vtp);

    // causal MFMA attention (one strip per wave, LPT order, 4 blk/CU)
    attn_mfma8<<<dim3(2048), 256, 0, stream>>>(qkvb, Kp, Vtp, headsb);

    // output projection
    gemm_nt_lds<float><<<dim3(BB * SS / 128, DD / 128), 256, 0, stream>>>(
        headsb, wob, out, BB * SS, DD, DD);
}

// Round 3
// 277.643 us; speedup vs baseline: 1.5837x; 1.1513x over previous
//
#include <hip/hip_runtime.h>
#include <hip/hip_bf16.h>

// Problem constants (B=4, S=2048, D=1024, H=16, DK=64)
#define BB 4
#define SS 2048
#define DD 1024
#define HH 16
#define DKK 64

typedef __bf16 bf16x8 __attribute__((ext_vector_type(8)));
typedef float floatx4 __attribute__((ext_vector_type(4)));

#if __has_builtin(__builtin_amdgcn_exp2f)
#define EXP2(x) __builtin_amdgcn_exp2f(x)
#else
#define EXP2(x) exp2f(x)
#endif

__device__ __forceinline__ float b2f(unsigned short u) {
    union { unsigned int i; float f; } c;
    c.i = ((unsigned int)u) << 16;
    return c.f;
}
__device__ __forceinline__ unsigned short f2b(float f) {
    unsigned int i = __float_as_uint(f);
    unsigned int r = (i + 0x7FFFu + ((i >> 16) & 1u)) >> 16;  // RNE
    return (unsigned short)r;
}
// cheap round-half-up bf16 pair pack: (lo, hi) -> u32
__device__ __forceinline__ unsigned int pkpair(float a, float b) {
    unsigned int ia = (__float_as_uint(a) + 0x8000u) >> 16;
    unsigned int ib = (__float_as_uint(b) + 0x8000u) & 0xffff0000u;
    return ia | ib;
}

// async global->LDS, 16 B per lane; LDS dst = wave-uniform base + lane*16
__device__ __forceinline__ void gload_lds16(const unsigned short* g,
                                            unsigned short* l) {
    __builtin_amdgcn_global_load_lds(
        (const __attribute__((address_space(1))) unsigned int*)g,
        (__attribute__((address_space(3))) unsigned int*)l, 16, 0, 0);
}

// ---------------------------------------------------------------------------
// fp32 -> bf16 conversion, 4 elems/thread
// ---------------------------------------------------------------------------
__global__ void cvt_f32_bf16(const float* __restrict__ in,
                             unsigned short* __restrict__ out, int n4) {
    int i = blockIdx.x * blockDim.x + threadIdx.x;
    if (i >= n4) return;
    float4 v = ((const float4*)in)[i];
    ushort4 o;
    o.x = f2b(v.x); o.y = f2b(v.y); o.z = f2b(v.z); o.w = f2b(v.w);
    ((ushort4*)out)[i] = o;
}

// ---------------------------------------------------------------------------
// 8-phase counted-vmcnt NT GEMM (T2+T3+T4+T5 per 256-wide template).
// BM=256, BN=128, BK=64. 512 threads = 8 waves (4M x 2N), wave tile 64x64.
// LDS 96 KiB dynamic: A dbuf 2x[256][64] + B dbuf 2x[128][64] bf16, both
// XOR-swizzled (byte ^= (row16&6)<<3) on BOTH sides: pre-swizzled global
// source for global_load_lds (LDS dest stays linear) + XOR'd ds_read.
// Schedule per K-tile: stage tile t+1 (6 instrs/wave) -> s_waitcnt vmcnt(6)
// (counted, never 0 mid-loop) -> raw s_barrier -> 4 phases {ds_read ||
// lgkmcnt(0)+sched_barrier || setprio-wrapped 8-MFMA cluster || s_barrier}.
// ---------------------------------------------------------------------------
template <typename CT>
__global__ __launch_bounds__(512, 2) void gemm_nt_8ph(
    const unsigned short* __restrict__ A,
    const unsigned short* __restrict__ B,
    CT* __restrict__ C, int M, int N, int K) {
    extern __shared__ unsigned short lds[];
    unsigned short* At = lds;                 // [2][256][64]
    unsigned short* Bt = lds + 2 * 256 * 64;  // [2][128][64]

    const int tid  = threadIdx.x;
    const int lane = tid & 63;
    const int w    = tid >> 6;                // 0..7
    const int wm   = (w >> 1) * 64;           // 4 waves along M
    const int wn   = (w & 1) * 64;            // 2 waves along N

    const int m0 = blockIdx.x * 256;
    const int n0 = blockIdx.y * 128;

    const int row16 = lane & 15;
    const int part  = lane >> 4;
    const int rbase = part * 4;

    // staging: lane covers row (lane>>3), 16B chunk (lane&7), swizzled col
    const int srow  = lane >> 3;
    const int scol  = ((lane & 7) * 8) ^ ((srow & 6) << 2);  // shorts

    const unsigned short* Ag = A + (size_t)(m0 + srow) * K + scol;
    const unsigned short* Bg = B + (size_t)(n0 + srow) * K + scol;

    const int NT = K >> 6;
    floatx4 acc[4][4] = {};

    const int shr = (row16 & 6) << 2;  // read-side XOR (shorts)

#define STAGE(t, bb)                                                        \
    {                                                                       \
        const size_t koff = (size_t)(t) * 64;                               \
        _Pragma("unroll") for (int a = 0; a < 4; ++a) {                     \
            const int rb = (w * 4 + a) * 8;                                 \
            gload_lds16(Ag + (size_t)rb * K + koff,                         \
                        At + (bb) * 16384 + rb * 64);                       \
        }                                                                   \
        _Pragma("unroll") for (int bi = 0; bi < 2; ++bi) {                  \
            const int rb = (w * 2 + bi) * 8;                                \
            gload_lds16(Bg + (size_t)rb * K + koff,                         \
                        Bt + (bb) * 8192 + rb * 64);                        \
        }                                                                   \
    }

    STAGE(0, 0);

    for (int t = 0; t < NT; ++t) {
        const int cur = t & 1;
        if (t + 1 < NT) {
            STAGE(t + 1, cur ^ 1);
            asm volatile("s_waitcnt vmcnt(6)" ::: "memory");
        } else {
            asm volatile("s_waitcnt vmcnt(0)" ::: "memory");
        }
        __builtin_amdgcn_sched_barrier(0);
        __builtin_amdgcn_s_barrier();

        const unsigned short* Ab = At + cur * 16384;
        const unsigned short* Bb = Bt + cur * 8192;

        // B fragments for the wave's 64 cols, held across all phases
        bf16x8 bf[4][2];
#pragma unroll
        for (int j = 0; j < 4; ++j)
#pragma unroll
            for (int u = 0; u < 2; ++u)
                bf[j][u] = *(const bf16x8*)(Bb + (wn + j * 16 + row16) * 64 +
                                            ((u * 32 + part * 8) ^ shr));

#pragma unroll
        for (int qm = 0; qm < 2; ++qm) {
            bf16x8 af[2][2];
#pragma unroll
            for (int i = 0; i < 2; ++i)
#pragma unroll
                for (int u = 0; u < 2; ++u)
                    af[i][u] = *(const bf16x8*)(
                        Ab + (wm + (qm * 2 + i) * 16 + row16) * 64 +
                        ((u * 32 + part * 8) ^ shr));
#pragma unroll
            for (int qn = 0; qn < 2; ++qn) {
                __builtin_amdgcn_s_barrier();
                asm volatile("s_waitcnt lgkmcnt(0)" ::: "memory");
                __builtin_amdgcn_sched_barrier(0);
                __builtin_amdgcn_s_setprio(1);
#pragma unroll
                for (int i = 0; i < 2; ++i)
#pragma unroll
                    for (int j = 0; j < 2; ++j)
#pragma unroll
                        for (int u = 0; u < 2; ++u)
                            acc[qm * 2 + i][qn * 2 + j] =
                                __builtin_amdgcn_mfma_f32_16x16x32_bf16(
                                    af[i][u], bf[qn * 2 + j][u],
                                    acc[qm * 2 + i][qn * 2 + j], 0, 0, 0);
                __builtin_amdgcn_s_setprio(0);
                __builtin_amdgcn_sched_barrier(0);
                __builtin_amdgcn_s_barrier();
            }
        }
    }
#undef STAGE

#pragma unroll
    for (int i = 0; i < 4; ++i) {
#pragma unroll
        for (int j = 0; j < 4; ++j) {
            const int row = m0 + wm + i * 16 + rbase;
            const int col = n0 + wn + j * 16 + row16;
#pragma unroll
            for (int r = 0; r < 4; ++r) {
                size_t idx = (size_t)(row + r) * N + col;
                if constexpr (sizeof(CT) == 2) C[idx] = f2b(acc[i][j][r]);
                else                           C[idx] = acc[i][j][r];
            }
        }
    }
}

// ---------------------------------------------------------------------------
// repack_kv (unchanged): fragment-linear K / V^T tiles per (b,h,stile64).
// ---------------------------------------------------------------------------
__global__ void repack_kv(const unsigned short* __restrict__ qkv,
                          unsigned short* __restrict__ Kp,
                          unsigned short* __restrict__ Vt) {
    __shared__ unsigned short Vs[64][72];
    const int st = blockIdx.x, h = blockIdx.y, b = blockIdx.z;
    const int tid = threadIdx.x;
    const size_t base = ((size_t)((b * HH + h) * (SS / 64) + st)) * 4096;

#pragma unroll
    for (int p = 0; p < 2; ++p) {
        const int row = p * 32 + (tid >> 3);
        const int chunk = tid & 7;
        size_t src = (size_t)(b * SS + st * 64 + row) * (3 * DD) +
                     DD + h * DKK + chunk * 8;
        uint4 kv = *(const uint4*)(qkv + src);
        *(uint4*)(Kp + base + (chunk >> 2) * 2048 + row * 32 + (chunk & 3) * 8) = kv;
        uint4 vv = *(const uint4*)(qkv + src + DD);
        *(uint4*)&Vs[row][chunk * 8] = vv;
    }
    __syncthreads();
#pragma unroll
    for (int p = 0; p < 2; ++p) {
        const int dk = p * 32 + (tid >> 3);
        const int s8 = tid & 7;
        union { unsigned short u[8]; uint4 v; } pk;
#pragma unroll
        for (int j = 0; j < 8; ++j) pk.u[j] = Vs[s8 * 8 + j][dk];
        *(uint4*)(Vt + base + (s8 >> 2) * 2048 + dk * 32 + (s8 & 3) * 8) = pk.v;
    }
}

// ---------------------------------------------------------------------------
// MFMA flash attention v6 (causal) — REVERTED VERBATIM (measured 87 us).
// LDS/barrier-free + complementary strip pairing for perfect load balance.
// Wave slot j handles q-strips j and 63-j of one (b,h): ntiles sums to 33
// for EVERY wave. K/V fragments loaded once per tile feed both strips.
// Grid 512 blocks (2/CU), 2048 uniform waves.
// ---------------------------------------------------------------------------
struct StripState {
    bf16x8 qf[2][2];
    floatx4 O[2][4];
    float mrow[2], lrow[2];
    int q0w;
};

__device__ __forceinline__ void strip_init(
    StripState& S, const unsigned short* __restrict__ qkv,
    int b, int h, int q0w, int row16, int part) {
    const float c1 = 0.180336884f;  // 0.125 * log2(e)
    S.q0w = q0w;
#pragma unroll
    for (int qt = 0; qt < 2; ++qt) {
        S.mrow[qt] = -1e30f;
        S.lrow[qt] = 0.f;
#pragma unroll
        for (int dt = 0; dt < 4; ++dt) S.O[qt][dt] = floatx4{0, 0, 0, 0};
#pragma unroll
        for (int u = 0; u < 2; ++u) {
            const unsigned short* qp = qkv +
                (size_t)(b * SS + q0w + qt * 16 + row16) * (3 * DD) +
                h * DKK + u * 32 + part * 8;
            union { uint4 r; unsigned short us[8]; } raw;
            raw.r = *(const uint4*)qp;
            union { unsigned short us[8]; bf16x8 v; } sq;
#pragma unroll
            for (int j = 0; j < 8; ++j) sq.us[j] = f2b(b2f(raw.us[j]) * c1);
            S.qf[qt][u] = sq.v;
        }
    }
}

__device__ __forceinline__ void strip_tile(
    StripState& S, int k0, const bf16x8 kf[2][4], const bf16x8 vf[2][4],
    int row16, int part, int rbase) {
#pragma unroll
    for (int qt = 0; qt < 2; ++qt) {
        // ---- S^T: lane holds q=row16, s = kt*16 + rbase + r ----
        floatx4 sc[4] = {};
#pragma unroll
        for (int u = 0; u < 2; ++u)
#pragma unroll
            for (int kt = 0; kt < 4; ++kt)
                sc[kt] = __builtin_amdgcn_mfma_f32_16x16x32_bf16(
                    kf[u][kt], S.qf[qt][u], sc[kt], 0, 0, 0);

        const int qa = S.q0w + qt * 16 + row16;
        const bool full = (k0 + 63 <= S.q0w + qt * 16);
        float mx = -1e30f;
#pragma unroll
        for (int kt = 0; kt < 4; ++kt)
#pragma unroll
            for (int r = 0; r < 4; ++r) {
                float s = sc[kt][r];  // log2-scaled via Q
                if (!full) {
                    int ka = k0 + kt * 16 + rbase + r;
                    s = (ka <= qa) ? s : -1e30f;
                }
                sc[kt][r] = s;
                mx = fmaxf(mx, s);
            }
        mx = fmaxf(mx, __shfl_xor(mx, 16));
        mx = fmaxf(mx, __shfl_xor(mx, 32));
        float mnew = fmaxf(S.mrow[qt], mx);
        float alpha = EXP2(S.mrow[qt] - mnew);

        float ps = 0.f;
        unsigned int pk[4][2];
#pragma unroll
        for (int kt = 0; kt < 4; ++kt) {
            float e0 = EXP2(sc[kt][0] - mnew);
            float e1 = EXP2(sc[kt][1] - mnew);
            float e2 = EXP2(sc[kt][2] - mnew);
            float e3 = EXP2(sc[kt][3] - mnew);
            ps += (e0 + e1) + (e2 + e3);
            pk[kt][0] = pkpair(e0, e1);
            pk[kt][1] = pkpair(e2, e3);
        }
        ps += __shfl_xor(ps, 16);
        ps += __shfl_xor(ps, 32);
        S.lrow[qt] = S.lrow[qt] * alpha + ps;
        S.mrow[qt] = mnew;

#pragma unroll
        for (int dt = 0; dt < 4; ++dt) S.O[qt][dt] *= alpha;

        // ---- P^T B-frags (kt-select AFTER shuffle; dest-part algebra) ----
        const int l0 = row16 + ((part & 1) * 2 + 0) * 16;
        const int l1 = row16 + ((part & 1) * 2 + 1) * 16;
        const bool hi = (part >> 1);
#pragma unroll
        for (int u = 0; u < 2; ++u) {
            unsigned int lo00 = (unsigned int)__shfl((int)pk[2 * u][0], l0);
            unsigned int lo01 = (unsigned int)__shfl((int)pk[2 * u][1], l0);
            unsigned int lo10 = (unsigned int)__shfl((int)pk[2 * u][0], l1);
            unsigned int lo11 = (unsigned int)__shfl((int)pk[2 * u][1], l1);
            unsigned int hi00 = (unsigned int)__shfl((int)pk[2 * u + 1][0], l0);
            unsigned int hi01 = (unsigned int)__shfl((int)pk[2 * u + 1][1], l0);
            unsigned int hi10 = (unsigned int)__shfl((int)pk[2 * u + 1][0], l1);
            unsigned int hi11 = (unsigned int)__shfl((int)pk[2 * u + 1][1], l1);
            union { unsigned int u32[4]; bf16x8 v; } P;
            P.u32[0] = hi ? hi00 : lo00;
            P.u32[1] = hi ? hi01 : lo01;
            P.u32[2] = hi ? hi10 : lo10;
            P.u32[3] = hi ? hi11 : lo11;
#pragma unroll
            for (int dt = 0; dt < 4; ++dt)
                S.O[qt][dt] = __builtin_amdgcn_mfma_f32_16x16x32_bf16(
                    vf[u][dt], P.v, S.O[qt][dt], 0, 0, 0);
        }
    }
}

__device__ __forceinline__ void strip_store(
    StripState& S, unsigned short* __restrict__ heads,
    int b, int h, int row16, int rbase) {
#pragma unroll
    for (int qt = 0; qt < 2; ++qt) {
        float inv = 1.f / S.lrow[qt];
#pragma unroll
        for (int dt = 0; dt < 4; ++dt) {
            ushort4 o4;
            o4.x = f2b(S.O[qt][dt][0] * inv);
            o4.y = f2b(S.O[qt][dt][1] * inv);
            o4.z = f2b(S.O[qt][dt][2] * inv);
            o4.w = f2b(S.O[qt][dt][3] * inv);
            size_t base = (size_t)(b * SS + S.q0w + qt * 16 + row16) * DD +
                          h * DKK + dt * 16 + rbase;
            *(ushort4*)&heads[base] = o4;
        }
    }
}

__global__ __launch_bounds__(256, 2) void attn_mfma6(
    const unsigned short* __restrict__ qkv,
    const unsigned short* __restrict__ Kp,
    const unsigned short* __restrict__ Vt,
    unsigned short* __restrict__ heads) {
    const int tid  = threadIdx.x;
    const int lane = tid & 63;
    const int w    = tid >> 6;

    // XCD mapping: 8 blocks of one (b,h) pinned to xcd = bx & 7
    const int bx   = blockIdx.x;              // 0..511
    const int xcd  = bx & 7;
    const int slot = bx >> 3;                 // 0..63
    const int pair = xcd * 8 + (slot >> 3);   // 0..63 = b*16+h
    const int blk  = slot & 7;                // 0..7
    const int b = pair >> 4, h = pair & 15;

    const int jA = blk * 4 + w;               // 0..31 (light strip)
    const int jB = 63 - jA;                   // 32..63 (heavy strip)
    const int ntA = jA / 2 + 1;               // tiles for strip A
    const int ntB = jB / 2 + 1;               // tiles for strip B (>= 17)

    const int row16 = lane & 15;
    const int part  = lane >> 4;
    const int rbase = part * 4;

    StripState SA, SB;
    strip_init(SA, qkv, b, h, jA * 32, row16, part);
    strip_init(SB, qkv, b, h, jB * 32, row16, part);

    const size_t tb = (size_t)pair * (SS / 64) * 4096;

    for (int t = 0; t < ntB; ++t) {
        const int k0 = t * 64;
        const unsigned short* kbase = Kp + tb + (size_t)t * 4096;
        const unsigned short* vbase = Vt + tb + (size_t)t * 4096;
        bf16x8 kf[2][4], vf[2][4];
#pragma unroll
        for (int u = 0; u < 2; ++u)
#pragma unroll
            for (int i = 0; i < 4; ++i) {
                kf[u][i] = *(const bf16x8*)(kbase + u * 2048 +
                                            (i * 16 + row16) * 32 + part * 8);
                vf[u][i] = *(const bf16x8*)(vbase + u * 2048 +
                                            (i * 16 + row16) * 32 + part * 8);
            }
        strip_tile(SB, k0, kf, vf, row16, part, rbase);
        if (t < ntA) strip_tile(SA, k0, kf, vf, row16, part, rbase);
    }

    strip_store(SA, heads, b, h, row16, rbase);
    strip_store(SB, heads, b, h, row16, rbase);
}

// ---------------------------------------------------------------------------
extern "C" void kernel_launch(void* const* d_in, const int* in_sizes, int n_in,
                              void* d_out, int out_size, void* d_ws,
                              size_t ws_size, hipStream_t stream) {
    const float* x    = (const float*)d_in[0];
    const float* Wqkv = (const float*)d_in[1];
    const float* Wo   = (const float*)d_in[2];
    float* out = (float*)d_out;

    const size_t NX  = (size_t)BB * SS * DD;
    const size_t NWQ = (size_t)3 * DD * DD;
    const size_t NWO = (size_t)DD * DD;
    const size_t NKV = (size_t)BB * HH * SS * DKK;

    unsigned short* xb     = (unsigned short*)d_ws;
    unsigned short* wqkvb  = xb + NX;
    unsigned short* wob    = wqkvb + NWQ;
    unsigned short* qkvb   = wob + NWO;
    unsigned short* headsb = qkvb + (size_t)BB * SS * 3 * DD;
    unsigned short* Kp     = headsb + NX;
    unsigned short* Vtp    = Kp + NKV;

    static bool attr_done = false;
    if (!attr_done) {
        hipFuncSetAttribute(
            reinterpret_cast<const void*>(&gemm_nt_8ph<unsigned short>),
            hipFuncAttributeMaxDynamicSharedMemorySize, 98304);
        hipFuncSetAttribute(
            reinterpret_cast<const void*>(&gemm_nt_8ph<float>),
            hipFuncAttributeMaxDynamicSharedMemorySize, 98304);
        attr_done = true;
    }

    cvt_f32_bf16<<<(int)(NX / 4 / 256), 256, 0, stream>>>(x, xb, (int)(NX / 4));
    cvt_f32_bf16<<<(int)(NWQ / 4 / 256), 256, 0, stream>>>(Wqkv, wqkvb, (int)(NWQ / 4));
    cvt_f32_bf16<<<(int)(NWO / 4 / 256), 256, 0, stream>>>(Wo, wob, (int)(NWO / 4));

    // QKV projection: 32 x 24 = 768 blocks = 3 balanced rounds at 1 blk/CU
    gemm_nt_8ph<unsigned short><<<dim3(BB * SS / 256, 3 * DD / 128), 512,
                                  98304, stream>>>(xb, wqkvb, qkvb,
                                                   BB * SS, 3 * DD, DD);

    // repack K/V into MFMA-ready fragment-linear tiles
    repack_kv<<<dim3(SS / 64, HH, BB), 256, 0, stream>>>(qkvb, Kp, Vtp);

    // causal MFMA attention (v6, balanced complementary strips)
    attn_mfma6<<<dim3(512), 256, 0, stream>>>(qkvb, Kp, Vtp, headsb);

    // output projection: 32 x 8 = 256 blocks = exactly 1 blk/CU
    gemm_nt_8ph<float><<<dim3(BB * SS / 256, DD / 128), 512, 98304, stream>>>(
        headsb, wob, out, BB * SS, DD, DD);
}

// Round 4
// 262.181 us; speedup vs baseline: 1.6771x; 1.0590x over previous
//
#include <hip/hip_runtime.h>
#include <hip/hip_bf16.h>

// Problem constants (B=4, S=2048, D=1024, H=16, DK=64)
#define BB 4
#define SS 2048
#define DD 1024
#define HH 16
#define DKK 64

typedef __bf16 bf16x8 __attribute__((ext_vector_type(8)));
typedef float floatx4 __attribute__((ext_vector_type(4)));

#if __has_builtin(__builtin_amdgcn_exp2f)
#define EXP2(x) __builtin_amdgcn_exp2f(x)
#else
#define EXP2(x) exp2f(x)
#endif

__device__ __forceinline__ float b2f(unsigned short u) {
    union { unsigned int i; float f; } c;
    c.i = ((unsigned int)u) << 16;
    return c.f;
}
__device__ __forceinline__ unsigned short f2b(float f) {
    unsigned int i = __float_as_uint(f);
    unsigned int r = (i + 0x7FFFu + ((i >> 16) & 1u)) >> 16;  // RNE
    return (unsigned short)r;
}
// cheap round-half-up bf16 pair pack: (lo, hi) -> u32
__device__ __forceinline__ unsigned int pkpair(float a, float b) {
    unsigned int ia = (__float_as_uint(a) + 0x8000u) >> 16;
    unsigned int ib = (__float_as_uint(b) + 0x8000u) & 0xffff0000u;
    return ia | ib;
}

// async global->LDS, 16 B per lane; LDS dst = wave-uniform base + lane*16
__device__ __forceinline__ void gload_lds16(const unsigned short* g,
                                            unsigned short* l) {
    __builtin_amdgcn_global_load_lds(
        (const __attribute__((address_space(1))) unsigned int*)g,
        (__attribute__((address_space(3))) unsigned int*)l, 16, 0, 0);
}

// ---------------------------------------------------------------------------
// fp32 -> bf16 conversion, 4 elems/thread
// ---------------------------------------------------------------------------
__global__ void cvt_f32_bf16(const float* __restrict__ in,
                             unsigned short* __restrict__ out, int n4) {
    int i = blockIdx.x * blockDim.x + threadIdx.x;
    if (i >= n4) return;
    float4 v = ((const float4*)in)[i];
    ushort4 o;
    o.x = f2b(v.x); o.y = f2b(v.y); o.z = f2b(v.z); o.w = f2b(v.w);
    ((ushort4*)out)[i] = o;
}

// ---------------------------------------------------------------------------
// Triple-buffered counted-vmcnt NT GEMM. BM=256, BN=128, BK=64.
// 512 threads = 8 waves (4M x 2N), wave tile 64x64, acc 4x4 frags.
// LDS 144 KiB = 3 x (A 256x64 + B 128x64) bf16, XOR-swizzled
// (byte ^= (row&7)<<4, 8 slots -> 2-way = free) on BOTH sides.
// Pipeline: stage(t+2) issued inside tile t => vmcnt(6) at tile-t top waits
// only for stage(t), issued TWO tiles (~700+cy) earlier: truly non-blocking;
// stage(t+1)'s 6 loads stay in flight across the barrier (T4).
// Per K-tile: 4 barriers, 2 phases x {ds_reads; barrier; lgkmcnt(0);
// setprio-wrapped 16 MFMA}.
// ---------------------------------------------------------------------------
template <typename CT>
__global__ __launch_bounds__(512, 2) void gemm_nt_3buf(
    const unsigned short* __restrict__ A,
    const unsigned short* __restrict__ B,
    CT* __restrict__ C, int M, int N, int K) {
    extern __shared__ unsigned short lds[];  // 3 * 24576 shorts

    const int tid  = threadIdx.x;
    const int lane = tid & 63;
    const int w    = tid >> 6;                // 0..7
    const int wm   = (w >> 1) * 64;           // 4 waves along M
    const int wn   = (w & 1) * 64;            // 2 waves along N

    const int m0 = blockIdx.x * 256;
    const int n0 = blockIdx.y * 128;

    const int row16 = lane & 15;
    const int part  = lane >> 4;
    const int rbase = part * 4;

    // staging: thread t covers LDS linear offset t*8 shorts per round;
    // source col pre-swizzled so linear LDS == swizzled layout.
    const int srow = tid >> 3;                               // 0..63
    const int scol = ((tid & 7) * 8) ^ ((srow & 7) << 3);    // shorts
    const unsigned short* Ag = A + (size_t)(m0 + srow) * K + scol;
    const unsigned short* Bg = B + (size_t)(n0 + srow) * K + scol;

    const int NT = K >> 6;
    floatx4 acc[4][4] = {};

    const int shr = (row16 & 7) << 3;  // read-side XOR (shorts)

#define STAGE3(t, bb)                                                       \
    {                                                                       \
        const size_t koff = (size_t)(t) * 64;                               \
        unsigned short* Abuf = lds + (bb) * 24576;                          \
        unsigned short* Bbuf = Abuf + 16384;                                \
        _Pragma("unroll") for (int r = 0; r < 4; ++r)                       \
            gload_lds16(Ag + (size_t)(r * 64) * K + koff,                   \
                        Abuf + r * 4096 + w * 512);                         \
        _Pragma("unroll") for (int r = 0; r < 2; ++r)                       \
            gload_lds16(Bg + (size_t)(r * 64) * K + koff,                   \
                        Bbuf + r * 4096 + w * 512);                         \
    }

    STAGE3(0, 0);
    STAGE3(1, 1);

    int cur = 0;
    for (int t = 0; t < NT; ++t) {
        // buffer `cur` was staged two tiles ago; 6 newest loads (tile t+1)
        // may stay in flight.
        if (t + 1 < NT) {
            asm volatile("s_waitcnt vmcnt(6)" ::: "memory");
        } else {
            asm volatile("s_waitcnt vmcnt(0)" ::: "memory");
        }
        __builtin_amdgcn_sched_barrier(0);
        __builtin_amdgcn_s_barrier();  // (A) tile entry

        if (t + 2 < NT) {
            int nb = cur + 2;
            if (nb >= 3) nb -= 3;
            STAGE3(t + 2, nb);
        }

        const unsigned short* Ab = lds + cur * 24576;
        const unsigned short* Bb = Ab + 16384;

        bf16x8 bf[4][2], af[2][2];
#pragma unroll
        for (int j = 0; j < 4; ++j)
#pragma unroll
            for (int u = 0; u < 2; ++u)
                bf[j][u] = *(const bf16x8*)(Bb + (wn + j * 16 + row16) * 64 +
                                            ((u * 32 + part * 8) ^ shr));
#pragma unroll
        for (int i = 0; i < 2; ++i)
#pragma unroll
            for (int u = 0; u < 2; ++u)
                af[i][u] = *(const bf16x8*)(Ab + (wm + i * 16 + row16) * 64 +
                                            ((u * 32 + part * 8) ^ shr));

        __builtin_amdgcn_s_barrier();  // (B)
        asm volatile("s_waitcnt lgkmcnt(0)" ::: "memory");
        __builtin_amdgcn_sched_barrier(0);
        __builtin_amdgcn_s_setprio(1);
#pragma unroll
        for (int i = 0; i < 2; ++i)
#pragma unroll
            for (int j = 0; j < 4; ++j)
#pragma unroll
                for (int u = 0; u < 2; ++u)
                    acc[i][j] = __builtin_amdgcn_mfma_f32_16x16x32_bf16(
                        af[i][u], bf[j][u], acc[i][j], 0, 0, 0);
        __builtin_amdgcn_s_setprio(0);
        __builtin_amdgcn_sched_barrier(0);
        __builtin_amdgcn_s_barrier();  // (C)

#pragma unroll
        for (int i = 0; i < 2; ++i)
#pragma unroll
            for (int u = 0; u < 2; ++u)
                af[i][u] = *(const bf16x8*)(
                    Ab + (wm + (2 + i) * 16 + row16) * 64 +
                    ((u * 32 + part * 8) ^ shr));

        __builtin_amdgcn_s_barrier();  // (D)
        asm volatile("s_waitcnt lgkmcnt(0)" ::: "memory");
        __builtin_amdgcn_sched_barrier(0);
        __builtin_amdgcn_s_setprio(1);
#pragma unroll
        for (int i = 0; i < 2; ++i)
#pragma unroll
            for (int j = 0; j < 4; ++j)
#pragma unroll
                for (int u = 0; u < 2; ++u)
                    acc[2 + i][j] = __builtin_amdgcn_mfma_f32_16x16x32_bf16(
                        af[i][u], bf[j][u], acc[2 + i][j], 0, 0, 0);
        __builtin_amdgcn_s_setprio(0);
        __builtin_amdgcn_sched_barrier(0);

        ++cur;
        if (cur >= 3) cur -= 3;
    }
#undef STAGE3

#pragma unroll
    for (int i = 0; i < 4; ++i) {
#pragma unroll
        for (int j = 0; j < 4; ++j) {
            const int row = m0 + wm + i * 16 + rbase;
            const int col = n0 + wn + j * 16 + row16;
#pragma unroll
            for (int r = 0; r < 4; ++r) {
                size_t idx = (size_t)(row + r) * N + col;
                if constexpr (sizeof(CT) == 2) C[idx] = f2b(acc[i][j][r]);
                else                           C[idx] = acc[i][j][r];
            }
        }
    }
}

// ---------------------------------------------------------------------------
// repack_kv (unchanged): fragment-linear K / V^T tiles per (b,h,stile64).
// ---------------------------------------------------------------------------
__global__ void repack_kv(const unsigned short* __restrict__ qkv,
                          unsigned short* __restrict__ Kp,
                          unsigned short* __restrict__ Vt) {
    __shared__ unsigned short Vs[64][72];
    const int st = blockIdx.x, h = blockIdx.y, b = blockIdx.z;
    const int tid = threadIdx.x;
    const size_t base = ((size_t)((b * HH + h) * (SS / 64) + st)) * 4096;

#pragma unroll
    for (int p = 0; p < 2; ++p) {
        const int row = p * 32 + (tid >> 3);
        const int chunk = tid & 7;
        size_t src = (size_t)(b * SS + st * 64 + row) * (3 * DD) +
                     DD + h * DKK + chunk * 8;
        uint4 kv = *(const uint4*)(qkv + src);
        *(uint4*)(Kp + base + (chunk >> 2) * 2048 + row * 32 + (chunk & 3) * 8) = kv;
        uint4 vv = *(const uint4*)(qkv + src + DD);
        *(uint4*)&Vs[row][chunk * 8] = vv;
    }
    __syncthreads();
#pragma unroll
    for (int p = 0; p < 2; ++p) {
        const int dk = p * 32 + (tid >> 3);
        const int s8 = tid & 7;
        union { unsigned short u[8]; uint4 v; } pk;
#pragma unroll
        for (int j = 0; j < 8; ++j) pk.u[j] = Vs[s8 * 8 + j][dk];
        *(uint4*)(Vt + base + (s8 >> 2) * 2048 + dk * 32 + (s8 & 3) * 8) = pk.v;
    }
}

// ---------------------------------------------------------------------------
// MFMA flash attention v6 + defer-max (T13): skip the alpha-rescale when
// the tile max doesn't exceed the running max by >8 (log2 domain). P values
// then bounded by 2^8; O-accum is f32, normalized at the end.
// Structure otherwise identical to the measured-87us v6.
// ---------------------------------------------------------------------------
struct StripState {
    bf16x8 qf[2][2];
    floatx4 O[2][4];
    float mrow[2], lrow[2];
    int q0w;
};

__device__ __forceinline__ void strip_init(
    StripState& S, const unsigned short* __restrict__ qkv,
    int b, int h, int q0w, int row16, int part) {
    const float c1 = 0.180336884f;  // 0.125 * log2(e)
    S.q0w = q0w;
#pragma unroll
    for (int qt = 0; qt < 2; ++qt) {
        S.mrow[qt] = -1e30f;
        S.lrow[qt] = 0.f;
#pragma unroll
        for (int dt = 0; dt < 4; ++dt) S.O[qt][dt] = floatx4{0, 0, 0, 0};
#pragma unroll
        for (int u = 0; u < 2; ++u) {
            const unsigned short* qp = qkv +
                (size_t)(b * SS + q0w + qt * 16 + row16) * (3 * DD) +
                h * DKK + u * 32 + part * 8;
            union { uint4 r; unsigned short us[8]; } raw;
            raw.r = *(const uint4*)qp;
            union { unsigned short us[8]; bf16x8 v; } sq;
#pragma unroll
            for (int j = 0; j < 8; ++j) sq.us[j] = f2b(b2f(raw.us[j]) * c1);
            S.qf[qt][u] = sq.v;
        }
    }
}

__device__ __forceinline__ void strip_tile(
    StripState& S, int k0, const bf16x8 kf[2][4], const bf16x8 vf[2][4],
    int row16, int part, int rbase) {
#pragma unroll
    for (int qt = 0; qt < 2; ++qt) {
        // ---- S^T: lane holds q=row16, s = kt*16 + rbase + r ----
        floatx4 sc[4] = {};
#pragma unroll
        for (int u = 0; u < 2; ++u)
#pragma unroll
            for (int kt = 0; kt < 4; ++kt)
                sc[kt] = __builtin_amdgcn_mfma_f32_16x16x32_bf16(
                    kf[u][kt], S.qf[qt][u], sc[kt], 0, 0, 0);

        const int qa = S.q0w + qt * 16 + row16;
        const bool full = (k0 + 63 <= S.q0w + qt * 16);
        float mx = -1e30f;
#pragma unroll
        for (int kt = 0; kt < 4; ++kt)
#pragma unroll
            for (int r = 0; r < 4; ++r) {
                float s = sc[kt][r];  // log2-scaled via Q
                if (!full) {
                    int ka = k0 + kt * 16 + rbase + r;
                    s = (ka <= qa) ? s : -1e30f;
                }
                sc[kt][r] = s;
                mx = fmaxf(mx, s);
            }
        mx = fmaxf(mx, __shfl_xor(mx, 16));
        mx = fmaxf(mx, __shfl_xor(mx, 32));

        // defer-max (T13): wave-uniform skip of the rescale
        const bool resc = !__all(mx - S.mrow[qt] <= 8.f);
        float mnew = resc ? fmaxf(S.mrow[qt], mx) : S.mrow[qt];

        float ps = 0.f;
        unsigned int pk[4][2];
#pragma unroll
        for (int kt = 0; kt < 4; ++kt) {
            float e0 = EXP2(sc[kt][0] - mnew);
            float e1 = EXP2(sc[kt][1] - mnew);
            float e2 = EXP2(sc[kt][2] - mnew);
            float e3 = EXP2(sc[kt][3] - mnew);
            ps += (e0 + e1) + (e2 + e3);
            pk[kt][0] = pkpair(e0, e1);
            pk[kt][1] = pkpair(e2, e3);
        }
        ps += __shfl_xor(ps, 16);
        ps += __shfl_xor(ps, 32);
        if (resc) {
            float alpha = EXP2(S.mrow[qt] - mnew);
            S.lrow[qt] = S.lrow[qt] * alpha + ps;
            S.mrow[qt] = mnew;
#pragma unroll
            for (int dt = 0; dt < 4; ++dt) S.O[qt][dt] *= alpha;
        } else {
            S.lrow[qt] += ps;
        }

        // ---- P^T B-frags (kt-select AFTER shuffle; dest-part algebra) ----
        const int l0 = row16 + ((part & 1) * 2 + 0) * 16;
        const int l1 = row16 + ((part & 1) * 2 + 1) * 16;
        const bool hi = (part >> 1);
#pragma unroll
        for (int u = 0; u < 2; ++u) {
            unsigned int lo00 = (unsigned int)__shfl((int)pk[2 * u][0], l0);
            unsigned int lo01 = (unsigned int)__shfl((int)pk[2 * u][1], l0);
            unsigned int lo10 = (unsigned int)__shfl((int)pk[2 * u][0], l1);
            unsigned int lo11 = (unsigned int)__shfl((int)pk[2 * u][1], l1);
            unsigned int hi00 = (unsigned int)__shfl((int)pk[2 * u + 1][0], l0);
            unsigned int hi01 = (unsigned int)__shfl((int)pk[2 * u + 1][1], l0);
            unsigned int hi10 = (unsigned int)__shfl((int)pk[2 * u + 1][0], l1);
            unsigned int hi11 = (unsigned int)__shfl((int)pk[2 * u + 1][1], l1);
            union { unsigned int u32[4]; bf16x8 v; } P;
            P.u32[0] = hi ? hi00 : lo00;
            P.u32[1] = hi ? hi01 : lo01;
            P.u32[2] = hi ? hi10 : lo10;
            P.u32[3] = hi ? hi11 : lo11;
#pragma unroll
            for (int dt = 0; dt < 4; ++dt)
                S.O[qt][dt] = __builtin_amdgcn_mfma_f32_16x16x32_bf16(
                    vf[u][dt], P.v, S.O[qt][dt], 0, 0, 0);
        }
    }
}

__device__ __forceinline__ void strip_store(
    StripState& S, unsigned short* __restrict__ heads,
    int b, int h, int row16, int rbase) {
#pragma unroll
    for (int qt = 0; qt < 2; ++qt) {
        float inv = 1.f / S.lrow[qt];
#pragma unroll
        for (int dt = 0; dt < 4; ++dt) {
            ushort4 o4;
            o4.x = f2b(S.O[qt][dt][0] * inv);
            o4.y = f2b(S.O[qt][dt][1] * inv);
            o4.z = f2b(S.O[qt][dt][2] * inv);
            o4.w = f2b(S.O[qt][dt][3] * inv);
            size_t base = (size_t)(b * SS + S.q0w + qt * 16 + row16) * DD +
                          h * DKK + dt * 16 + rbase;
            *(ushort4*)&heads[base] = o4;
        }
    }
}

__global__ __launch_bounds__(256, 2) void attn_mfma6(
    const unsigned short* __restrict__ qkv,
    const unsigned short* __restrict__ Kp,
    const unsigned short* __restrict__ Vt,
    unsigned short* __restrict__ heads) {
    const int tid  = threadIdx.x;
    const int lane = tid & 63;
    const int w    = tid >> 6;

    // XCD mapping: 8 blocks of one (b,h) pinned to xcd = bx & 7
    const int bx   = blockIdx.x;              // 0..511
    const int xcd  = bx & 7;
    const int slot = bx >> 3;                 // 0..63
    const int pair = xcd * 8 + (slot >> 3);   // 0..63 = b*16+h
    const int blk  = slot & 7;                // 0..7
    const int b = pair >> 4, h = pair & 15;

    const int jA = blk * 4 + w;               // 0..31 (light strip)
    const int jB = 63 - jA;                   // 32..63 (heavy strip)
    const int ntA = jA / 2 + 1;               // tiles for strip A
    const int ntB = jB / 2 + 1;               // tiles for strip B (>= 17)

    const int row16 = lane & 15;
    const int part  = lane >> 4;
    const int rbase = part * 4;

    StripState SA, SB;
    strip_init(SA, qkv, b, h, jA * 32, row16, part);
    strip_init(SB, qkv, b, h, jB * 32, row16, part);

    const size_t tb = (size_t)pair * (SS / 64) * 4096;

    for (int t = 0; t < ntB; ++t) {
        const int k0 = t * 64;
        const unsigned short* kbase = Kp + tb + (size_t)t * 4096;
        const unsigned short* vbase = Vt + tb + (size_t)t * 4096;
        bf16x8 kf[2][4], vf[2][4];
#pragma unroll
        for (int u = 0; u < 2; ++u)
#pragma unroll
            for (int i = 0; i < 4; ++i) {
                kf[u][i] = *(const bf16x8*)(kbase + u * 2048 +
                                            (i * 16 + row16) * 32 + part * 8);
                vf[u][i] = *(const bf16x8*)(vbase + u * 2048 +
                                            (i * 16 + row16) * 32 + part * 8);
            }
        strip_tile(SB, k0, kf, vf, row16, part, rbase);
        if (t < ntA) strip_tile(SA, k0, kf, vf, row16, part, rbase);
    }

    strip_store(SA, heads, b, h, row16, rbase);
    strip_store(SB, heads, b, h, row16, rbase);
}

// ---------------------------------------------------------------------------
extern "C" void kernel_launch(void* const* d_in, const int* in_sizes, int n_in,
                              void* d_out, int out_size, void* d_ws,
                              size_t ws_size, hipStream_t stream) {
    const float* x    = (const float*)d_in[0];
    const float* Wqkv = (const float*)d_in[1];
    const float* Wo   = (const float*)d_in[2];
    float* out = (float*)d_out;

    const size_t NX  = (size_t)BB * SS * DD;
    const size_t NWQ = (size_t)3 * DD * DD;
    const size_t NWO = (size_t)DD * DD;
    const size_t NKV = (size_t)BB * HH * SS * DKK;

    unsigned short* xb     = (unsigned short*)d_ws;
    unsigned short* wqkvb  = xb + NX;
    unsigned short* wob    = wqkvb + NWQ;
    unsigned short* qkvb   = wob + NWO;
    unsigned short* headsb = qkvb + (size_t)BB * SS * 3 * DD;
    unsigned short* Kp     = headsb + NX;
    unsigned short* Vtp    = Kp + NKV;

    static bool attr_done = false;
    if (!attr_done) {
        hipFuncSetAttribute(
            reinterpret_cast<const void*>(&gemm_nt_3buf<unsigned short>),
            hipFuncAttributeMaxDynamicSharedMemorySize, 147456);
        hipFuncSetAttribute(
            reinterpret_cast<const void*>(&gemm_nt_3buf<float>),
            hipFuncAttributeMaxDynamicSharedMemorySize, 147456);
        attr_done = true;
    }

    cvt_f32_bf16<<<(int)(NX / 4 / 256), 256, 0, stream>>>(x, xb, (int)(NX / 4));
    cvt_f32_bf16<<<(int)(NWQ / 4 / 256), 256, 0, stream>>>(Wqkv, wqkvb, (int)(NWQ / 4));
    cvt_f32_bf16<<<(int)(NWO / 4 / 256), 256, 0, stream>>>(Wo, wob, (int)(NWO / 4));

    // QKV projection: 32 x 24 = 768 blocks = 3 balanced rounds at 1 blk/CU
    gemm_nt_3buf<unsigned short><<<dim3(BB * SS / 256, 3 * DD / 128), 512,
                                   147456, stream>>>(xb, wqkvb, qkvb,
                                                     BB * SS, 3 * DD, DD);

    // repack K/V into MFMA-ready fragment-linear tiles
    repack_kv<<<dim3(SS / 64, HH, BB), 256, 0, stream>>>(qkvb, Kp, Vtp);

    // causal MFMA attention (v6 + defer-max)
    attn_mfma6<<<dim3(512), 256, 0, stream>>>(qkvb, Kp, Vtp, headsb);

    // output projection: 32 x 8 = 256 blocks = exactly 1 blk/CU
    gemm_nt_3buf<float><<<dim3(BB * SS / 256, DD / 128), 512, 147456, stream>>>(
        headsb, wob, out, BB * SS, DD, DD);
}